// Round 6
// baseline (137.599 us; speedup 1.0000x reference)
//
#include <hip/hip_runtime.h>
#include <hip/hip_bf16.h>
#include <stdint.h>

typedef int v4i __attribute__((ext_vector_type(4)));

#define GPTR(p) ((const __attribute__((address_space(1))) void*)(p))
#define LPTR(p) ((__attribute__((address_space(3))) void*)(p))

__device__ __forceinline__ float wave_max(float m) {
#pragma unroll
  for (int off = 32; off > 0; off >>= 1)
    m = fmaxf(m, __shfl_xor(m, off, 64));
  return m;
}

// branch-free erf (Abramowitz-Stegun 7.1.26), |err| <= 1.5e-7 absolute
__device__ __forceinline__ float fast_erf(float x) {
  const float ax = fabsf(x);
  const float t = __builtin_amdgcn_rcpf(fmaf(0.3275911f, ax, 1.0f));
  float p = fmaf(1.061405429f, t, -1.453152027f);
  p = fmaf(p, t, 1.421413741f);
  p = fmaf(p, t, -0.284496736f);
  p = fmaf(p, t, 0.254829592f);
  const float e = __expf(-ax * ax);
  const float r = 1.0f - p * t * e;
  return copysignf(r, x);
}

__device__ __forceinline__ float gelu_exact(float f) {
  return 0.5f * f * (1.0f + fast_erf(f * 0.70710678118654752f));
}

// fused absmax of {x*smul, w1, w2} -> scal[0..2], one atomic per block
__global__ void absmax3_kernel(const float* __restrict__ x, int nx4,
                               const float* __restrict__ smul,
                               const float* __restrict__ w1, int nw14,
                               const float* __restrict__ w2, int nw24,
                               unsigned* __restrict__ scal) {
  __shared__ float red[4];
  const int bid = blockIdx.x;
  const float4* s4;
  int n4, b0, nb;
  float s = 1.0f;
  unsigned* dst;
  if (bid < 512)      { s4 = (const float4*)x;  n4 = nx4;  s = smul[0]; dst = scal;     b0 = bid;       nb = 512; }
  else if (bid < 640) { s4 = (const float4*)w1; n4 = nw14;              dst = scal + 1; b0 = bid - 512; nb = 128; }
  else                { s4 = (const float4*)w2; n4 = nw24;              dst = scal + 2; b0 = bid - 640; nb = 128; }
  float m = 0.0f;
  const int stride = nb * blockDim.x;
  for (int i = b0 * blockDim.x + threadIdx.x; i < n4; i += stride) {
    float4 v = s4[i];
    m = fmaxf(m, fabsf(v.x * s));
    m = fmaxf(m, fabsf(v.y * s));
    m = fmaxf(m, fabsf(v.z * s));
    m = fmaxf(m, fabsf(v.w * s));
  }
  m = wave_max(m);
  if ((threadIdx.x & 63) == 0) red[threadIdx.x >> 6] = m;
  __syncthreads();
  if (threadIdx.x == 0)
    atomicMax(dst, __float_as_uint(fmaxf(fmaxf(red[0], red[1]), fmaxf(red[2], red[3]))));
}

// fused quantize of {x*smul, w1, w2} -> qx, qw1, qw2
__global__ void quantize3_kernel(const float* __restrict__ x, int nx4,
                                 const float* __restrict__ smul,
                                 const float* __restrict__ w1, int nw14,
                                 const float* __restrict__ w2, int nw24,
                                 const unsigned* __restrict__ scal,
                                 int8_t* __restrict__ qx,
                                 int8_t* __restrict__ qw1,
                                 int8_t* __restrict__ qw2) {
  const int bid = blockIdx.x;
  const float4* s4;
  char4* d4;
  int n4, b0, nb;
  float s = 1.0f, mx;
  if (bid < 2048)      { s4 = (const float4*)x;  d4 = (char4*)qx;  n4 = nx4;  s = smul[0]; mx = __uint_as_float(scal[0]); b0 = bid;        nb = 2048; }
  else if (bid < 2176) { s4 = (const float4*)w1; d4 = (char4*)qw1; n4 = nw14;              mx = __uint_as_float(scal[1]); b0 = bid - 2048; nb = 128; }
  else                 { s4 = (const float4*)w2; d4 = (char4*)qw2; n4 = nw24;              mx = __uint_as_float(scal[2]); b0 = bid - 2176; nb = 128; }
  const float scale = mx / 127.0f;  // exact IEEE divide, matches reference
  const int stride = nb * blockDim.x;
  for (int i = b0 * blockDim.x + threadIdx.x; i < n4; i += stride) {
    float4 v = s4[i];
    char4 qq;
    qq.x = (signed char)(int)rintf(fminf(fmaxf((v.x * s) / scale, -128.0f), 127.0f));
    qq.y = (signed char)(int)rintf(fminf(fmaxf((v.y * s) / scale, -128.0f), 127.0f));
    qq.z = (signed char)(int)rintf(fminf(fmaxf((v.z * s) / scale, -128.0f), 127.0f));
    qq.w = (signed char)(int)rintf(fminf(fmaxf((v.w * s) / scale, -128.0f), 127.0f));
    d4[i] = qq;
  }
}

// reduce partial maxima of raw fc1 output f; s_h numerator = max|gelu|:
// gelu increasing for f>0; |gelu| <= max(gelu(max_f), 0.1699702) (global min |gelu|).
__global__ void reduce_scale_kernel(const float* __restrict__ partial, int n,
                                    unsigned* __restrict__ scal) {
  __shared__ float red[4];
  float m = -3.4e38f;
  for (int i = threadIdx.x; i < n; i += blockDim.x) m = fmaxf(m, partial[i]);
  m = wave_max(m);
  if ((threadIdx.x & 63) == 0) red[threadIdx.x >> 6] = m;
  __syncthreads();
  if (threadIdx.x == 0) {
    m = fmaxf(fmaxf(red[0], red[1]), fmaxf(red[2], red[3]));
    const float sx = __uint_as_float(scal[0]) / 127.0f;
    const float sw = __uint_as_float(scal[1]) / 127.0f;
    const float max_f = m * (sw * sx);  // same fp ops as per-element path
    scal[3] = __float_as_uint(fmaxf(gelu_exact(max_f), 0.1699702f));
  }
}

// C = A[M,K] @ B[N,K]^T, int8 -> int32 MFMA. BN=128, BK=64, 2x2 waves.
// BM = 128 (GEMM1) or 64 (GEMM2: more blocks -> drain overlap).
// C layout: n = lane&15, m = (lane>>4)*4 + reg (verified r1-r3).
// EPI 0: per-block max of (max_m acc) + bias -> partial[]
// EPI 1: qh = rint(clip(gelu(f*s1)/s_h)) int8 via swizzled LDS repack,
//        then 4 dwordx4 full-line stores per thread.
// EPI 2: out = (acc+b2)*s2 f32, direct stores (64B groups per instr).
template <int EPI, int BM>
__global__ __launch_bounds__(256, BM == 128 ? 4 : 5)
void gemm_i8_kernel(const int8_t* __restrict__ A, const int8_t* __restrict__ B,
                    const float* __restrict__ bias,
                    const unsigned* __restrict__ scal,
                    float* __restrict__ partial,
                    int8_t* __restrict__ out_i8,
                    float* __restrict__ out_f32,
                    int N, int K, int GN) {
  constexpr int FR = BM / 32;       // wave-row fragments (4 or 2)
  constexpr int AH = BM / 64;       // A half-tiles staged (2 or 1)
  __shared__ __align__(16) int8_t lA[2][BM * 64];
  __shared__ __align__(16) int8_t lB[2][128 * 64];

  // bijective XCD swizzle (m204): contiguous work chunk per XCD
  const int nwg = gridDim.x;
  const int q = nwg >> 3, rr = nwg & 7;
  const int xcd = blockIdx.x & 7, sub = blockIdx.x >> 3;
  const int wg = (xcd < rr ? xcd * (q + 1) : rr * (q + 1) + (xcd - rr) * q) + sub;
  const int bx = wg % GN;   // n-tile (fastest: shares A panel)
  const int by = wg / GN;   // m-tile

  const int t = threadIdx.x;
  const int lane = t & 63;
  const int wave = t >> 6;
  const int wr = wave >> 1;
  const int wc = wave & 1;
  const size_t m0 = (size_t)by * BM;
  const int n0 = bx * 128;

  const int8_t* Ab = A + m0 * (size_t)K;
  const int8_t* Bb = B + (size_t)n0 * (size_t)K;

  v4i acc[FR][4] = {};
  const int KT = K >> 6;  // BK = 64

  // Staging: linear LDS fill; XOR slot-swizzle f(row)=(row>>1)&3 pre-applied
  // on the GLOBAL source address (both-sides rule). 64B rows = 4 x 16B slots.
  // Measured 0 bank conflicts (r4/r5).
  const int row0 = t >> 2;
  const int ss = (t & 3) ^ ((row0 >> 1) & 3);
  const int ubase = __builtin_amdgcn_readfirstlane((t & 192) * 16);
  const size_t srcA0 = (size_t)row0 * K + (size_t)(ss * 16);
  const size_t srcA1 = (size_t)(row0 + 64) * K + (size_t)(ss * 16);

  auto stage = [&](int buf, int kt) {
    const int8_t* ga = Ab + kt * 64;
    const int8_t* gb = Bb + kt * 64;
    __builtin_amdgcn_global_load_lds(GPTR(ga + srcA0), LPTR(&lA[buf][ubase]), 16, 0, 0);
    if constexpr (AH == 2)
      __builtin_amdgcn_global_load_lds(GPTR(ga + srcA1), LPTR(&lA[buf][4096 + ubase]), 16, 0, 0);
    __builtin_amdgcn_global_load_lds(GPTR(gb + srcA0), LPTR(&lB[buf][ubase]), 16, 0, 0);
    __builtin_amdgcn_global_load_lds(GPTR(gb + srcA1), LPTR(&lB[buf][4096 + ubase]), 16, 0, 0);
  };

  const int r15 = lane & 15;
  const int q4 = lane >> 4;

  auto compute = [&](int buf) {
    v4i af[FR], bf[4];
#pragma unroll
    for (int fr = 0; fr < FR; ++fr) {
      const int row = wr * (BM / 2) + fr * 16 + r15;
      const int slot = q4 ^ ((row >> 1) & 3);
      af[fr] = *(const v4i*)(&lA[buf][row * 64 + slot * 16]);
    }
#pragma unroll
    for (int fc = 0; fc < 4; ++fc) {
      const int row = wc * 64 + fc * 16 + r15;
      const int slot = q4 ^ ((row >> 1) & 3);
      bf[fc] = *(const v4i*)(&lB[buf][row * 64 + slot * 16]);
    }
#pragma unroll
    for (int fr = 0; fr < FR; ++fr)
#pragma unroll
      for (int fc = 0; fc < 4; ++fc)
        acc[fr][fc] = __builtin_amdgcn_mfma_i32_16x16x64_i8(af[fr], bf[fc], acc[fr][fc], 0, 0, 0);
  };

  stage(0, 0);
  asm volatile("s_waitcnt vmcnt(0)" ::: "memory");
  __syncthreads();
  int cur = 0;
  for (int kt = 1; kt < KT; ++kt) {
    stage(cur ^ 1, kt);   // issue next-tile loads BEFORE compute
    compute(cur);
    __syncthreads();      // drains vmcnt+lgkmcnt: next tile ready
    cur ^= 1;
  }
  compute(cur);

  const int rb = q4 * 4;

  if constexpr (EPI == 0) {
    // max_m(acc[m][n] + b[n]) = (max_m acc[:,n]) + b[n]: int max, one add.
    float lm = -3.4e38f;
#pragma unroll
    for (int fc = 0; fc < 4; ++fc) {
      int im = acc[0][fc][0];
#pragma unroll
      for (int fr = 0; fr < FR; ++fr)
#pragma unroll
        for (int r = 0; r < 4; ++r) im = max(im, acc[fr][fc][r]);
      const float bv = bias[n0 + wc * 64 + fc * 16 + r15];
      lm = fmaxf(lm, (float)im + bv);
    }
    lm = wave_max(lm);
    __syncthreads();               // all LDS reads done -> reuse lA as scratch
    float* red = (float*)lA;
    if (lane == 0) red[wave] = lm;
    __syncthreads();
    if (t == 0)
      partial[wg] = fmaxf(fmaxf(red[0], red[1]), fmaxf(red[2], red[3]));
  } else if constexpr (EPI == 1) {
    const float sx = __uint_as_float(scal[0]) / 127.0f;
    const float sw = __uint_as_float(scal[1]) / 127.0f;
    const float s1 = sw * sx;
    const float sh = __uint_as_float(scal[3]) / 127.0f;
    const float inv_sh = __builtin_amdgcn_rcpf(sh);
    __syncthreads();                 // all compute() LDS reads complete
    int8_t* qt = (int8_t*)lA;        // 16 KiB = 128x128 repack tile, swizzled
    // write swizzle: stored_col = col ^ (q4<<4). Per store instr the 4
    // q4-groups land in 4 distinct 16B column slots -> 16 banks, and the 4
    // byte-lanes per dword merge -> conflict-free.
#pragma unroll
    for (int fc = 0; fc < 4; ++fc) {
      const int col = wc * 64 + fc * 16 + r15;
      const float bv = bias[n0 + col];
      const float bvs = bv * s1;  // f = fma(cvt(acc), s1, bv*s1) == (acc+bv)*s1
#pragma unroll
      for (int fr = 0; fr < 4; ++fr) {
        const int rowb = wr * 64 + fr * 16 + rb;
#pragma unroll
        for (int r = 0; r < 4; ++r) {
          const float f = fmaf((float)acc[fr][fc][r], s1, bvs);
          const float g = gelu_exact(f);
          const float qv = rintf(fminf(fmaxf(g * inv_sh, -128.0f), 127.0f));
          qt[(rowb + r) * 128 + (col ^ (q4 << 4))] = (int8_t)(int)qv;
        }
      }
    }
    __syncthreads();
#pragma unroll
    for (int v = 0; v < 4; ++v) {
      const int row = v * 32 + (t >> 3);
      const int colb = (t & 7) * 16;
      const int swz = ((row >> 2) & 3) << 4;
      *(v4i*)(out_i8 + (m0 + row) * (size_t)N + n0 + colb) =
          *(const v4i*)(qt + row * 128 + (colb ^ swz));
    }
  } else {
    const float sw2 = __uint_as_float(scal[2]) / 127.0f;
    const float sh = __uint_as_float(scal[3]) / 127.0f;
    const float x2max = 127.0f * sh;
    const float sx2 = x2max / 127.0f;
    const float s2 = sw2 * sx2;
#pragma unroll
    for (int fc = 0; fc < 4; ++fc) {
      const int n = n0 + wc * 64 + fc * 16 + r15;
      const float bv = bias[n];
      const float bvs = bv * s2;
#pragma unroll
      for (int fr = 0; fr < FR; ++fr) {
#pragma unroll
        for (int r = 0; r < 4; ++r) {
          const size_t m = m0 + (size_t)(wr * (BM / 2) + fr * 16 + rb + r);
          out_f32[m * (size_t)N + n] = fmaf((float)acc[fr][fc][r], s2, bvs);
        }
      }
    }
  }
}

extern "C" void kernel_launch(void* const* d_in, const int* in_sizes, int n_in,
                              void* d_out, int out_size, void* d_ws, size_t ws_size,
                              hipStream_t stream) {
  const float* x   = (const float*)d_in[0];
  const float* sxp = (const float*)d_in[1];
  const float* w1  = (const float*)d_in[2];
  const float* b1  = (const float*)d_in[3];
  const float* w2  = (const float*)d_in[4];
  const float* b2  = (const float*)d_in[5];

  const int H = in_sizes[3];      // 1536
  const int D = in_sizes[5];      // 384
  const int M = in_sizes[0] / D;  // 25216 = 197*128
  const int GM1 = M / 128;        // 197
  const int GM2 = M / 64;         // 394
  const int GN1 = H / 128;        // 12
  const int GN2 = D / 128;        // 3

  uint8_t* ws = (uint8_t*)d_ws;
  unsigned* scal = (unsigned*)ws;  // [0]=max|x2| [1]=max|w1| [2]=max|w2| [3]=max|g|
  size_t off = 256;
  float* partial = (float*)(ws + off); off += 16384;
  int8_t* qx  = (int8_t*)(ws + off); off += (size_t)M * D;
  int8_t* qw1 = (int8_t*)(ws + off); off += (size_t)H * D;
  int8_t* qw2 = (int8_t*)(ws + off); off += (size_t)D * H;
  int8_t* qh  = (int8_t*)(ws + off); off += (size_t)M * H;
  (void)ws_size; (void)n_in; (void)out_size;

  hipMemsetAsync(scal, 0, 16, stream);

  absmax3_kernel<<<dim3(768), dim3(256), 0, stream>>>(
      x, M * D / 4, sxp, w1, H * D / 4, w2, D * H / 4, scal);

  quantize3_kernel<<<dim3(2304), dim3(256), 0, stream>>>(
      x, M * D / 4, sxp, w1, H * D / 4, w2, D * H / 4, scal, qx, qw1, qw2);

  dim3 blk(256);
  dim3 g1(GN1 * GM1);  // 2364, 1D grid, swizzled in-kernel
  gemm_i8_kernel<0, 128><<<g1, blk, 0, stream>>>(qx, qw1, b1, scal, partial, nullptr, nullptr, H, D, GN1);
  reduce_scale_kernel<<<1, 256, 0, stream>>>(partial, GM1 * GN1, scal);
  gemm_i8_kernel<1, 128><<<g1, blk, 0, stream>>>(qx, qw1, b1, scal, nullptr, qh, nullptr, H, D, GN1);

  dim3 g2(GN2 * GM2);  // 1182
  gemm_i8_kernel<2, 64><<<g2, blk, 0, stream>>>(qh, qw2, b2, scal, nullptr, nullptr, (float*)d_out, D, H, GN2);
}

// Round 7
// 135.447 us; speedup vs baseline: 1.0159x; 1.0159x over previous
//
#include <hip/hip_runtime.h>
#include <hip/hip_bf16.h>
#include <stdint.h>
#include <math.h>

typedef int v4i __attribute__((ext_vector_type(4)));

#define GPTR(p) ((const __attribute__((address_space(1))) void*)(p))
#define LPTR(p) ((__attribute__((address_space(3))) void*)(p))

__device__ __forceinline__ float wave_max(float m) {
#pragma unroll
  for (int off = 32; off > 0; off >>= 1)
    m = fmaxf(m, __shfl_xor(m, off, 64));
  return m;
}

// tanh-form GELU via sigmoid: g = x * sigma(1.5957692*x*(1+0.044715x^2))
// sigma(y) = 1/(1+exp2(-1.442695*y)).  |g - gelu_erf| <= ~3e-4 absolute.
// 6 VALU + 2 TRANS per element (vs 15 VALU + 2 TRANS for the erf poly).
__device__ __forceinline__ float gelu_tanh(float x) {
  const float x2 = x * x;
  const float p = fmaf(0.044715f, x2, 1.0f);
  const float u = x * p;
  const float e = exp2f(-2.3022082f * u);  // -2*0.7978845608*1.4426950409
  return x * __builtin_amdgcn_rcpf(1.0f + e);
}

// fused absmax of {x*smul, w1, w2} -> scal[0..2], one atomic per block
__global__ void absmax3_kernel(const float* __restrict__ x, int nx4,
                               const float* __restrict__ smul,
                               const float* __restrict__ w1, int nw14,
                               const float* __restrict__ w2, int nw24,
                               unsigned* __restrict__ scal) {
  __shared__ float red[4];
  const int bid = blockIdx.x;
  const float4* s4;
  int n4, b0, nb;
  float s = 1.0f;
  unsigned* dst;
  if (bid < 512)      { s4 = (const float4*)x;  n4 = nx4;  s = smul[0]; dst = scal;     b0 = bid;       nb = 512; }
  else if (bid < 640) { s4 = (const float4*)w1; n4 = nw14;              dst = scal + 1; b0 = bid - 512; nb = 128; }
  else                { s4 = (const float4*)w2; n4 = nw24;              dst = scal + 2; b0 = bid - 640; nb = 128; }
  float m = 0.0f;
  const int stride = nb * blockDim.x;
  for (int i = b0 * blockDim.x + threadIdx.x; i < n4; i += stride) {
    float4 v = s4[i];
    m = fmaxf(m, fabsf(v.x * s));
    m = fmaxf(m, fabsf(v.y * s));
    m = fmaxf(m, fabsf(v.z * s));
    m = fmaxf(m, fabsf(v.w * s));
  }
  m = wave_max(m);
  if ((threadIdx.x & 63) == 0) red[threadIdx.x >> 6] = m;
  __syncthreads();
  if (threadIdx.x == 0)
    atomicMax(dst, __float_as_uint(fmaxf(fmaxf(red[0], red[1]), fmaxf(red[2], red[3]))));
}

// fused quantize of {x*smul, w1, w2} -> qx, qw1, qw2
__global__ void quantize3_kernel(const float* __restrict__ x, int nx4,
                                 const float* __restrict__ smul,
                                 const float* __restrict__ w1, int nw14,
                                 const float* __restrict__ w2, int nw24,
                                 const unsigned* __restrict__ scal,
                                 int8_t* __restrict__ qx,
                                 int8_t* __restrict__ qw1,
                                 int8_t* __restrict__ qw2) {
  const int bid = blockIdx.x;
  const float4* s4;
  char4* d4;
  int n4, b0, nb;
  float s = 1.0f, mx;
  if (bid < 2048)      { s4 = (const float4*)x;  d4 = (char4*)qx;  n4 = nx4;  s = smul[0]; mx = __uint_as_float(scal[0]); b0 = bid;        nb = 2048; }
  else if (bid < 2176) { s4 = (const float4*)w1; d4 = (char4*)qw1; n4 = nw14;              mx = __uint_as_float(scal[1]); b0 = bid - 2048; nb = 128; }
  else                 { s4 = (const float4*)w2; d4 = (char4*)qw2; n4 = nw24;              mx = __uint_as_float(scal[2]); b0 = bid - 2176; nb = 128; }
  const float scale = mx / 127.0f;  // exact IEEE divide, matches reference
  const int stride = nb * blockDim.x;
  for (int i = b0 * blockDim.x + threadIdx.x; i < n4; i += stride) {
    float4 v = s4[i];
    char4 qq;
    qq.x = (signed char)(int)rintf(fminf(fmaxf((v.x * s) / scale, -128.0f), 127.0f));
    qq.y = (signed char)(int)rintf(fminf(fmaxf((v.y * s) / scale, -128.0f), 127.0f));
    qq.z = (signed char)(int)rintf(fminf(fmaxf((v.z * s) / scale, -128.0f), 127.0f));
    qq.w = (signed char)(int)rintf(fminf(fmaxf((v.w * s) / scale, -128.0f), 127.0f));
    d4[i] = qq;
  }
}

// reduce partial maxima of raw fc1 output f; s_h numerator = max|gelu|:
// gelu increasing for f>0; |gelu| <= max(gelu(max_f), 0.1699702) (global min |gelu|).
// Uses gelu_tanh for consistency with the quantizing epilogue.
__global__ void reduce_scale_kernel(const float* __restrict__ partial, int n,
                                    unsigned* __restrict__ scal) {
  __shared__ float red[4];
  float m = -3.4e38f;
  for (int i = threadIdx.x; i < n; i += blockDim.x) m = fmaxf(m, partial[i]);
  m = wave_max(m);
  if ((threadIdx.x & 63) == 0) red[threadIdx.x >> 6] = m;
  __syncthreads();
  if (threadIdx.x == 0) {
    m = fmaxf(fmaxf(red[0], red[1]), fmaxf(red[2], red[3]));
    const float sx = __uint_as_float(scal[0]) / 127.0f;
    const float sw = __uint_as_float(scal[1]) / 127.0f;
    const float max_f = m * (sw * sx);  // same fp ops as per-element path
    scal[3] = __float_as_uint(fmaxf(gelu_tanh(max_f), 0.1699702f));
  }
}

#define CBAR()                          \
  do {                                  \
    __builtin_amdgcn_sched_barrier(0);  \
    __builtin_amdgcn_s_barrier();       \
    __builtin_amdgcn_sched_barrier(0);  \
  } while (0)

// C = A[M,K] @ B[N,K]^T, int8 -> int32 MFMA. BN=128, BK=64, 2x2 waves.
// 2-buffer loop, raw s_barrier + COUNTED vmcnt: next tile's loads stay in
// flight across compute (T4); lgkmcnt(0)+barrier protects buffer overwrite.
// C layout: n = lane&15, m = (lane>>4)*4 + reg (verified r1-r3).
template <int EPI, int BM>
__device__ __forceinline__
void gemm_body(const int8_t* __restrict__ A, const int8_t* __restrict__ B,
               const float* __restrict__ bias,
               const unsigned* __restrict__ scal,
               float* __restrict__ partial,
               int8_t* __restrict__ out_i8,
               float* __restrict__ out_f32,
               int N, int K, int GN) {
  constexpr int FR = BM / 32;       // wave-row fragments (4 or 2)
  constexpr int AH = BM / 64;       // A half-tiles staged (2 or 1)
  __shared__ __align__(16) int8_t lA[2][BM * 64];
  __shared__ __align__(16) int8_t lB[2][128 * 64];

  // bijective XCD swizzle (m204): contiguous work chunk per XCD
  const int nwg = gridDim.x;
  const int q = nwg >> 3, rr = nwg & 7;
  const int xcd = blockIdx.x & 7, sub = blockIdx.x >> 3;
  const int wg = (xcd < rr ? xcd * (q + 1) : rr * (q + 1) + (xcd - rr) * q) + sub;
  const int bx = wg % GN;   // n-tile (fastest: shares A panel)
  const int by = wg / GN;   // m-tile

  const int t = threadIdx.x;
  const int lane = t & 63;
  const int wave = t >> 6;
  const int wr = wave >> 1;
  const int wc = wave & 1;
  const size_t m0 = (size_t)by * BM;
  const int n0 = bx * 128;

  const int8_t* Ab = A + m0 * (size_t)K;
  const int8_t* Bb = B + (size_t)n0 * (size_t)K;

  v4i acc[FR][4] = {};
  const int KT = K >> 6;  // BK = 64

  // Staging: linear LDS fill; XOR slot-swizzle f(row)=(row>>1)&3 pre-applied
  // on the GLOBAL source address (both-sides rule). 64B rows = 4 x 16B slots.
  // Measured 0 bank conflicts (r4-r6).
  const int row0 = t >> 2;
  const int ss = (t & 3) ^ ((row0 >> 1) & 3);
  const int ubase = __builtin_amdgcn_readfirstlane((t & 192) * 16);
  const size_t srcA0 = (size_t)row0 * K + (size_t)(ss * 16);
  const size_t srcA1 = (size_t)(row0 + 64) * K + (size_t)(ss * 16);

  auto stage = [&](int buf, int kt) {
    const int8_t* ga = Ab + kt * 64;
    const int8_t* gb = Bb + kt * 64;
    __builtin_amdgcn_global_load_lds(GPTR(ga + srcA0), LPTR(&lA[buf][ubase]), 16, 0, 0);
    if constexpr (AH == 2)
      __builtin_amdgcn_global_load_lds(GPTR(ga + srcA1), LPTR(&lA[buf][4096 + ubase]), 16, 0, 0);
    __builtin_amdgcn_global_load_lds(GPTR(gb + srcA0), LPTR(&lB[buf][ubase]), 16, 0, 0);
    __builtin_amdgcn_global_load_lds(GPTR(gb + srcA1), LPTR(&lB[buf][4096 + ubase]), 16, 0, 0);
  };

  const int r15 = lane & 15;
  const int q4 = lane >> 4;

  auto compute = [&](int buf) {
    v4i af[FR], bf[4];
#pragma unroll
    for (int fr = 0; fr < FR; ++fr) {
      const int row = wr * (BM / 2) + fr * 16 + r15;
      const int slot = q4 ^ ((row >> 1) & 3);
      af[fr] = *(const v4i*)(&lA[buf][row * 64 + slot * 16]);
    }
#pragma unroll
    for (int fc = 0; fc < 4; ++fc) {
      const int row = wc * 64 + fc * 16 + r15;
      const int slot = q4 ^ ((row >> 1) & 3);
      bf[fc] = *(const v4i*)(&lB[buf][row * 64 + slot * 16]);
    }
#pragma unroll
    for (int fr = 0; fr < FR; ++fr)
#pragma unroll
      for (int fc = 0; fc < 4; ++fc)
        acc[fr][fc] = __builtin_amdgcn_mfma_i32_16x16x64_i8(af[fr], bf[fc], acc[fr][fc], 0, 0, 0);
  };

  // K-loop: counted vmcnt, loads for kt+1 stay in flight across compute(kt).
  stage(0, 0);
  int cur = 0;
  for (int kt = 0; kt < KT; ++kt) {
    if (kt + 1 < KT) {
      stage(cur ^ 1, kt + 1);
      // my kt-stage landed iff vmcnt <= loads(kt+1)
      if constexpr (AH == 2) asm volatile("s_waitcnt vmcnt(4)" ::: "memory");
      else                   asm volatile("s_waitcnt vmcnt(3)" ::: "memory");
    } else {
      asm volatile("s_waitcnt vmcnt(0)" ::: "memory");
    }
    CBAR();            // all waves' kt-stage landed
    compute(cur);
    if (kt + 1 < KT) {
      asm volatile("s_waitcnt lgkmcnt(0)" ::: "memory");  // my ds_reads of cur done
      CBAR();          // all waves done reading cur -> next iter may overwrite
    }
    cur ^= 1;
  }

  const int rb = q4 * 4;

  if constexpr (EPI == 0) {
    // max_m(acc[m][n] + b[n]) = (max_m acc[:,n]) + b[n]: int max, one add.
    float lm = -3.4e38f;
#pragma unroll
    for (int fc = 0; fc < 4; ++fc) {
      int im = acc[0][fc][0];
#pragma unroll
      for (int fr = 0; fr < FR; ++fr)
#pragma unroll
        for (int r = 0; r < 4; ++r) im = max(im, acc[fr][fc][r]);
      const float bv = bias[n0 + wc * 64 + fc * 16 + r15];
      lm = fmaxf(lm, (float)im + bv);
    }
    lm = wave_max(lm);
    __syncthreads();               // all LDS reads done -> reuse lA as scratch
    float* red = (float*)lA;
    if (lane == 0) red[wave] = lm;
    __syncthreads();
    if (t == 0)
      partial[wg] = fmaxf(fmaxf(red[0], red[1]), fmaxf(red[2], red[3]));
  } else if constexpr (EPI == 1) {
    const float sx = __uint_as_float(scal[0]) / 127.0f;
    const float sw = __uint_as_float(scal[1]) / 127.0f;
    const float s1 = sw * sx;
    const float sh = __uint_as_float(scal[3]) / 127.0f;
    const float inv_sh = __builtin_amdgcn_rcpf(sh);
    __syncthreads();                 // all compute() LDS reads complete
    int8_t* qt = (int8_t*)lA;        // 16 KiB = 128x128 repack tile, swizzled
    // write swizzle: stored_col = col ^ (q4<<4) -> conflict-free (r6: 0 conflicts)
#pragma unroll
    for (int fc = 0; fc < 4; ++fc) {
      const int col = wc * 64 + fc * 16 + r15;
      const float bv = bias[n0 + col];
      const float bvs = bv * s1;  // f = fma(cvt(acc), s1, bv*s1) == (acc+bv)*s1
#pragma unroll
      for (int fr = 0; fr < 4; ++fr) {
        const int rowb = wr * 64 + fr * 16 + rb;
#pragma unroll
        for (int r = 0; r < 4; ++r) {
          const float f = fmaf((float)acc[fr][fc][r], s1, bvs);
          const float g = gelu_tanh(f);
          const float qv = rintf(fminf(fmaxf(g * inv_sh, -128.0f), 127.0f));
          qt[(rowb + r) * 128 + (col ^ (q4 << 4))] = (int8_t)(int)qv;
        }
      }
    }
    __syncthreads();
#pragma unroll
    for (int v = 0; v < 4; ++v) {
      const int row = v * 32 + (t >> 3);
      const int colb = (t & 7) * 16;
      const int swz = ((row >> 2) & 3) << 4;
      *(v4i*)(out_i8 + (m0 + row) * (size_t)N + n0 + colb) =
          *(const v4i*)(qt + row * 128 + (colb ^ swz));
    }
  } else {
    const float sw2 = __uint_as_float(scal[2]) / 127.0f;
    const float sh = __uint_as_float(scal[3]) / 127.0f;
    const float x2max = 127.0f * sh;
    const float sx2 = x2max / 127.0f;
    const float s2 = sw2 * sx2;
#pragma unroll
    for (int fc = 0; fc < 4; ++fc) {
      const int n = n0 + wc * 64 + fc * 16 + r15;
      const float bv = bias[n];
      const float bvs = bv * s2;
#pragma unroll
      for (int fr = 0; fr < FR; ++fr) {
#pragma unroll
        for (int r = 0; r < 4; ++r) {
          const size_t m = m0 + (size_t)(wr * (BM / 2) + fr * 16 + rb + r);
          out_f32[m * (size_t)N + n] = fmaf((float)acc[fr][fc][r], s2, bvs);
        }
      }
    }
  }
}

__global__ __launch_bounds__(256, 4)
void gemm1_absmax_kernel(const int8_t* A, const int8_t* B, const float* bias,
                         const unsigned* scal, float* partial, int N, int K, int GN) {
  gemm_body<0, 128>(A, B, bias, scal, partial, nullptr, nullptr, N, K, GN);
}

__global__ __launch_bounds__(256, 4)
void gemm1_quant_kernel(const int8_t* A, const int8_t* B, const float* bias,
                        const unsigned* scal, int8_t* out_i8, int N, int K, int GN) {
  gemm_body<1, 128>(A, B, bias, scal, nullptr, out_i8, nullptr, N, K, GN);
}

__global__ __launch_bounds__(256, 5)
void gemm2_out_kernel(const int8_t* A, const int8_t* B, const float* bias,
                      const unsigned* scal, float* out_f32, int N, int K, int GN) {
  gemm_body<2, 64>(A, B, bias, scal, nullptr, nullptr, out_f32, N, K, GN);
}

extern "C" void kernel_launch(void* const* d_in, const int* in_sizes, int n_in,
                              void* d_out, int out_size, void* d_ws, size_t ws_size,
                              hipStream_t stream) {
  const float* x   = (const float*)d_in[0];
  const float* sxp = (const float*)d_in[1];
  const float* w1  = (const float*)d_in[2];
  const float* b1  = (const float*)d_in[3];
  const float* w2  = (const float*)d_in[4];
  const float* b2  = (const float*)d_in[5];

  const int H = in_sizes[3];      // 1536
  const int D = in_sizes[5];      // 384
  const int M = in_sizes[0] / D;  // 25216 = 197*128
  const int GM1 = M / 128;        // 197
  const int GM2 = M / 64;         // 394
  const int GN1 = H / 128;        // 12
  const int GN2 = D / 128;        // 3

  uint8_t* ws = (uint8_t*)d_ws;
  unsigned* scal = (unsigned*)ws;  // [0]=max|x2| [1]=max|w1| [2]=max|w2| [3]=max|g|
  size_t off = 256;
  float* partial = (float*)(ws + off); off += 16384;
  int8_t* qx  = (int8_t*)(ws + off); off += (size_t)M * D;
  int8_t* qw1 = (int8_t*)(ws + off); off += (size_t)H * D;
  int8_t* qw2 = (int8_t*)(ws + off); off += (size_t)D * H;
  int8_t* qh  = (int8_t*)(ws + off); off += (size_t)M * H;
  (void)ws_size; (void)n_in; (void)out_size;

  hipMemsetAsync(scal, 0, 16, stream);

  absmax3_kernel<<<dim3(768), dim3(256), 0, stream>>>(
      x, M * D / 4, sxp, w1, H * D / 4, w2, D * H / 4, scal);

  quantize3_kernel<<<dim3(2304), dim3(256), 0, stream>>>(
      x, M * D / 4, sxp, w1, H * D / 4, w2, D * H / 4, scal, qx, qw1, qw2);

  dim3 blk(256);
  dim3 g1(GN1 * GM1);  // 2364, 1D grid, swizzled in-kernel
  gemm1_absmax_kernel<<<g1, blk, 0, stream>>>(qx, qw1, b1, scal, partial, H, D, GN1);
  reduce_scale_kernel<<<1, 256, 0, stream>>>(partial, GM1 * GN1, scal);
  gemm1_quant_kernel<<<g1, blk, 0, stream>>>(qx, qw1, b1, scal, qh, H, D, GN1);

  dim3 g2(GN2 * GM2);  // 1182
  gemm2_out_kernel<<<g2, blk, 0, stream>>>(qh, qw2, b2, scal, (float*)d_out, D, H, GN2);
}

// Round 11
// 132.480 us; speedup vs baseline: 1.0386x; 1.0224x over previous
//
#include <hip/hip_runtime.h>
#include <hip/hip_bf16.h>
#include <stdint.h>

typedef int v4i __attribute__((ext_vector_type(4)));
typedef int v2i __attribute__((ext_vector_type(2)));

#define GPTR(p) ((const __attribute__((address_space(1))) void*)(p))
#define LPTR(p) ((__attribute__((address_space(3))) void*)(p))

__device__ __forceinline__ float wave_max(float m) {
#pragma unroll
  for (int off = 32; off > 0; off >>= 1)
    m = fmaxf(m, __shfl_xor(m, off, 64));
  return m;
}

// tanh-form GELU via sigmoid: g = x * sigma(1.5957692*x*(1+0.044715x^2))
// |g - gelu_erf| <= ~3e-4 absolute. Validated r7 (absmax 0.0156).
__device__ __forceinline__ float gelu_tanh(float x) {
  const float x2 = x * x;
  const float u = x * fmaf(0.044715f, x2, 1.0f);
  const float e = exp2f(-2.3022082f * u);
  return x * __builtin_amdgcn_rcpf(1.0f + e);
}

// fused absmax of {x*smul, w1, w2} -> scal[0..2], one atomic per block
__global__ void absmax3_kernel(const float* __restrict__ x, int nx4,
                               const float* __restrict__ smul,
                               const float* __restrict__ w1, int nw14,
                               const float* __restrict__ w2, int nw24,
                               unsigned* __restrict__ scal) {
  __shared__ float red[4];
  const int bid = blockIdx.x;
  const float4* s4;
  int n4, b0, nb;
  float s = 1.0f;
  unsigned* dst;
  if (bid < 512)      { s4 = (const float4*)x;  n4 = nx4;  s = smul[0]; dst = scal;     b0 = bid;       nb = 512; }
  else if (bid < 640) { s4 = (const float4*)w1; n4 = nw14;              dst = scal + 1; b0 = bid - 512; nb = 128; }
  else                { s4 = (const float4*)w2; n4 = nw24;              dst = scal + 2; b0 = bid - 640; nb = 128; }
  float m = 0.0f;
  const int stride = nb * blockDim.x;
  for (int i = b0 * blockDim.x + threadIdx.x; i < n4; i += stride) {
    float4 v = s4[i];
    m = fmaxf(m, fabsf(v.x * s));
    m = fmaxf(m, fabsf(v.y * s));
    m = fmaxf(m, fabsf(v.z * s));
    m = fmaxf(m, fabsf(v.w * s));
  }
  m = wave_max(m);
  if ((threadIdx.x & 63) == 0) red[threadIdx.x >> 6] = m;
  __syncthreads();
  if (threadIdx.x == 0)
    atomicMax(dst, __float_as_uint(fmaxf(fmaxf(red[0], red[1]), fmaxf(red[2], red[3]))));
}

// fused quantize of {x*smul, w1, w2} -> qx, qw1, qw2
__global__ void quantize3_kernel(const float* __restrict__ x, int nx4,
                                 const float* __restrict__ smul,
                                 const float* __restrict__ w1, int nw14,
                                 const float* __restrict__ w2, int nw24,
                                 const unsigned* __restrict__ scal,
                                 int8_t* __restrict__ qx,
                                 int8_t* __restrict__ qw1,
                                 int8_t* __restrict__ qw2) {
  const int bid = blockIdx.x;
  const float4* s4;
  char4* d4;
  int n4, b0, nb;
  float s = 1.0f, mx;
  if (bid < 2048)      { s4 = (const float4*)x;  d4 = (char4*)qx;  n4 = nx4;  s = smul[0]; mx = __uint_as_float(scal[0]); b0 = bid;        nb = 2048; }
  else if (bid < 2176) { s4 = (const float4*)w1; d4 = (char4*)qw1; n4 = nw14;              mx = __uint_as_float(scal[1]); b0 = bid - 2048; nb = 128; }
  else                 { s4 = (const float4*)w2; d4 = (char4*)qw2; n4 = nw24;              mx = __uint_as_float(scal[2]); b0 = bid - 2176; nb = 128; }
  const float scale = mx / 127.0f;  // exact IEEE divide, matches reference
  const int stride = nb * blockDim.x;
  for (int i = b0 * blockDim.x + threadIdx.x; i < n4; i += stride) {
    float4 v = s4[i];
    char4 qq;
    qq.x = (signed char)(int)rintf(fminf(fmaxf((v.x * s) / scale, -128.0f), 127.0f));
    qq.y = (signed char)(int)rintf(fminf(fmaxf((v.y * s) / scale, -128.0f), 127.0f));
    qq.z = (signed char)(int)rintf(fminf(fmaxf((v.z * s) / scale, -128.0f), 127.0f));
    qq.w = (signed char)(int)rintf(fminf(fmaxf((v.w * s) / scale, -128.0f), 127.0f));
    d4[i] = qq;
  }
}

// reduce partial maxima -> s_h numerator = max|gelu|.
// pre_scaled=0: partial holds raw (acc+bias) max, multiply by sw*sx first.
// pre_scaled=1: partial already holds f = (acc+bias)*s1 max (fused path).
// gelu increasing for f>0; |gelu| <= max(gelu(max_f), 0.1699702).
__global__ void reduce_scale_kernel(const float* __restrict__ partial, int n,
                                    unsigned* __restrict__ scal, int pre_scaled) {
  __shared__ float red[4];
  float m = -3.4e38f;
  for (int i = threadIdx.x; i < n; i += blockDim.x) m = fmaxf(m, partial[i]);
  m = wave_max(m);
  if ((threadIdx.x & 63) == 0) red[threadIdx.x >> 6] = m;
  __syncthreads();
  if (threadIdx.x == 0) {
    m = fmaxf(fmaxf(red[0], red[1]), fmaxf(red[2], red[3]));
    float max_f;
    if (pre_scaled) {
      max_f = m;  // already in f units (fused EPI3 stores scaled f)
    } else {
      const float sx = __uint_as_float(scal[0]) / 127.0f;
      const float sw = __uint_as_float(scal[1]) / 127.0f;
      max_f = m * (sw * sx);
    }
    scal[3] = __float_as_uint(fmaxf(gelu_tanh(max_f), 0.1699702f));
  }
}

// elementwise: qh = rint(clip(gelu(h16 * F_blk/32767) / s_h)). one block per
// 128x128 tile (matches gemm1 tiling; F_blk lookup is direct).
__global__ __launch_bounds__(256)
void quanth_kernel(const short* __restrict__ h16, const float* __restrict__ fscale,
                   const unsigned* __restrict__ scal, int8_t* __restrict__ qh,
                   int H, int GN) {
  const int tile = blockIdx.x;
  const int by = tile / GN, bx = tile % GN;
  const size_t m0 = (size_t)by * 128;
  const int n0 = bx * 128;
  const float fsc = fscale[tile] * (1.0f / 32767.0f);
  const float sh = __uint_as_float(scal[3]) / 127.0f;
  const float inv_sh = __builtin_amdgcn_rcpf(sh);
  const int t = threadIdx.x;
  const int r15 = t & 15;
#pragma unroll
  for (int v = 0; v < 8; ++v) {
    const int row = v * 16 + (t >> 4);
    const size_t base = (m0 + row) * (size_t)H + n0 + r15 * 8;
    const v4i raw = *(const v4i*)(&h16[base]);
    const short* sp = (const short*)&raw;
    signed char c[8];
#pragma unroll
    for (int j = 0; j < 8; ++j) {
      const float f = (float)sp[j] * fsc;
      const float g = gelu_tanh(f);
      c[j] = (signed char)(int)rintf(fminf(fmaxf(g * inv_sh, -128.0f), 127.0f));
    }
    *(v2i*)(&qh[base]) = *(const v2i*)c;
  }
}

#define CBAR()                          \
  do {                                  \
    __builtin_amdgcn_sched_barrier(0);  \
    __builtin_amdgcn_s_barrier();       \
    __builtin_amdgcn_sched_barrier(0);  \
  } while (0)

// C = A[M,K] @ B[N,K]^T, int8 -> int32 MFMA. BN=128, BK=64, 2x2 waves.
// r7-VERIFIED 2-buffer loop: counted vmcnt, raw s_barrier, lgkmcnt fence.
// C layout: n = lane&15, m = (lane>>4)*4 + reg (verified r1-r3).
// EPI 0: per-block max of raw acc+bias -> partial            (fallback)
// EPI 1: qh int8 via swizzled repack                         (fallback)
// EPI 2: out f32
// EPI 3: fused: max f -> partial (f units!), max|f| -> fscale,
//        h16 = rint(f*32767/F_blk) via swizzled int16 repack
template <int EPI, int BM>
__device__ __forceinline__
void gemm_body(const int8_t* __restrict__ A, const int8_t* __restrict__ B,
               const float* __restrict__ bias,
               const unsigned* __restrict__ scal,
               float* __restrict__ partial, float* __restrict__ fscale,
               int8_t* __restrict__ out_i8, short* __restrict__ out_i16,
               float* __restrict__ out_f32,
               int N, int K, int GN) {
  constexpr int FR = BM / 32;       // wave-row fragments (4 or 2)
  constexpr int AH = BM / 64;       // A half-tiles staged (2 or 1)
  __shared__ __align__(16) int8_t lds[2 * BM * 64 + 2 * 128 * 64];
  __shared__ float red8[8];
  int8_t (*lA)[BM * 64] = (int8_t(*)[BM * 64])lds;
  int8_t (*lB)[128 * 64] = (int8_t(*)[128 * 64])(lds + 2 * BM * 64);

  // bijective XCD swizzle (m204)
  const int nwg = gridDim.x;
  const int q = nwg >> 3, rr = nwg & 7;
  const int xcd = blockIdx.x & 7, sub = blockIdx.x >> 3;
  const int wg = (xcd < rr ? xcd * (q + 1) : rr * (q + 1) + (xcd - rr) * q) + sub;
  const int bx = wg % GN;   // n-tile fastest: shares A panel
  const int by = wg / GN;
  const int tid0 = by * GN + bx;   // unswizzled tile id (fscale/partial slot)

  const int t = threadIdx.x;
  const int lane = t & 63;
  const int wave = t >> 6;
  const int wr = wave >> 1;
  const int wc = wave & 1;
  const size_t m0 = (size_t)by * BM;
  const int n0 = bx * 128;

  const int8_t* Ab = A + m0 * (size_t)K;
  const int8_t* Bb = B + (size_t)n0 * (size_t)K;

  v4i acc[FR][4] = {};
  const int KT = K >> 6;  // BK=64; KT = 6 or 24

  // Staging: linear LDS fill; XOR slot-swizzle f(row)=(row>>1)&3 pre-applied
  // on the GLOBAL source (both-sides rule). 0 bank conflicts measured r4-r7.
  const int row0 = t >> 2;
  const int ss = (t & 3) ^ ((row0 >> 1) & 3);
  const int ubase = __builtin_amdgcn_readfirstlane((t & 192) * 16);
  const size_t srcA0 = (size_t)row0 * K + (size_t)(ss * 16);
  const size_t srcA1 = (size_t)(row0 + 64) * K + (size_t)(ss * 16);

  auto stage = [&](int buf, int kt) {
    const int8_t* ga = Ab + kt * 64;
    const int8_t* gb = Bb + kt * 64;
    __builtin_amdgcn_global_load_lds(GPTR(ga + srcA0), LPTR(&lA[buf][ubase]), 16, 0, 0);
    if constexpr (AH == 2)
      __builtin_amdgcn_global_load_lds(GPTR(ga + srcA1), LPTR(&lA[buf][4096 + ubase]), 16, 0, 0);
    __builtin_amdgcn_global_load_lds(GPTR(gb + srcA0), LPTR(&lB[buf][ubase]), 16, 0, 0);
    __builtin_amdgcn_global_load_lds(GPTR(gb + srcA1), LPTR(&lB[buf][4096 + ubase]), 16, 0, 0);
  };

  const int r15 = lane & 15;
  const int q4 = lane >> 4;

  auto compute = [&](int buf) {
    v4i af[FR], bf[4];
#pragma unroll
    for (int fr = 0; fr < FR; ++fr) {
      const int row = wr * (BM / 2) + fr * 16 + r15;
      const int slot = q4 ^ ((row >> 1) & 3);
      af[fr] = *(const v4i*)(&lA[buf][row * 64 + slot * 16]);
    }
#pragma unroll
    for (int fc = 0; fc < 4; ++fc) {
      const int row = wc * 64 + fc * 16 + r15;
      const int slot = q4 ^ ((row >> 1) & 3);
      bf[fc] = *(const v4i*)(&lB[buf][row * 64 + slot * 16]);
    }
#pragma unroll
    for (int fr = 0; fr < FR; ++fr)
#pragma unroll
      for (int fc = 0; fc < 4; ++fc)
        acc[fr][fc] = __builtin_amdgcn_mfma_i32_16x16x64_i8(af[fr], bf[fc], acc[fr][fc], 0, 0, 0);
  };

  // r7-verified K-loop: depth-1 prefetch, counted vmcnt.
  stage(0, 0);
  int cur = 0;
  for (int kt = 0; kt < KT; ++kt) {
    if (kt + 1 < KT) {
      stage(cur ^ 1, kt + 1);
      if constexpr (AH == 2) asm volatile("s_waitcnt vmcnt(4)" ::: "memory");
      else                   asm volatile("s_waitcnt vmcnt(3)" ::: "memory");
    } else {
      asm volatile("s_waitcnt vmcnt(0)" ::: "memory");
    }
    CBAR();            // all waves' stage(kt) landed
    compute(cur);
    if (kt + 1 < KT) {
      asm volatile("s_waitcnt lgkmcnt(0)" ::: "memory");
      CBAR();          // all waves done reading cur -> restage allowed
    }
    cur ^= 1;
  }

  const int rb = q4 * 4;

  if constexpr (EPI == 0) {
    float lm = -3.4e38f;
#pragma unroll
    for (int fc = 0; fc < 4; ++fc) {
      int im = acc[0][fc][0];
#pragma unroll
      for (int fr = 0; fr < FR; ++fr)
#pragma unroll
        for (int r = 0; r < 4; ++r) im = max(im, acc[fr][fc][r]);
      const float bv = bias[n0 + wc * 64 + fc * 16 + r15];
      lm = fmaxf(lm, (float)im + bv);
    }
    lm = wave_max(lm);
    if (lane == 0) red8[wave] = lm;
    __syncthreads();
    if (t == 0)
      partial[tid0] = fmaxf(fmaxf(red8[0], red8[1]), fmaxf(red8[2], red8[3]));
  } else if constexpr (EPI == 1) {
    const float sx = __uint_as_float(scal[0]) / 127.0f;
    const float sw = __uint_as_float(scal[1]) / 127.0f;
    const float s1 = sw * sx;
    const float sh = __uint_as_float(scal[3]) / 127.0f;
    const float inv_sh = __builtin_amdgcn_rcpf(sh);
    __syncthreads();
    int8_t* qt = lds;  // 16 KiB repack tile, col ^ (q4<<4) swizzle (0-conflict, r6)
#pragma unroll
    for (int fc = 0; fc < 4; ++fc) {
      const int col = wc * 64 + fc * 16 + r15;
      const float bvs = bias[n0 + col] * s1;
#pragma unroll
      for (int fr = 0; fr < 4; ++fr) {
        const int rowb = wr * 64 + fr * 16 + rb;
#pragma unroll
        for (int r = 0; r < 4; ++r) {
          const float f = fmaf((float)acc[fr][fc][r], s1, bvs);
          const float g = gelu_tanh(f);
          const float qv = rintf(fminf(fmaxf(g * inv_sh, -128.0f), 127.0f));
          qt[(rowb + r) * 128 + (col ^ (q4 << 4))] = (int8_t)(int)qv;
        }
      }
    }
    __syncthreads();
#pragma unroll
    for (int v = 0; v < 4; ++v) {
      const int row = v * 32 + (t >> 3);
      const int colb = (t & 7) * 16;
      const int swz = ((row >> 2) & 3) << 4;
      *(v4i*)(out_i8 + (m0 + row) * (size_t)N + n0 + colb) =
          *(const v4i*)(qt + row * 128 + (colb ^ swz));
    }
  } else if constexpr (EPI == 2) {
    const float sw2 = __uint_as_float(scal[2]) / 127.0f;
    const float sh = __uint_as_float(scal[3]) / 127.0f;
    const float s2 = sw2 * ((127.0f * sh) / 127.0f);
#pragma unroll
    for (int fc = 0; fc < 4; ++fc) {
      const int n = n0 + wc * 64 + fc * 16 + r15;
      const float bvs = bias[n] * s2;
#pragma unroll
      for (int fr = 0; fr < FR; ++fr)
#pragma unroll
        for (int r = 0; r < 4; ++r) {
          const size_t m = m0 + (size_t)(wr * (BM / 2) + fr * 16 + rb + r);
          out_f32[m * (size_t)N + n] = fmaf((float)acc[fr][fc][r], s2, bvs);
        }
    }
  } else {  // EPI == 3: fused absmax + int16 staging
    const float sx = __uint_as_float(scal[0]) / 127.0f;
    const float sw = __uint_as_float(scal[1]) / 127.0f;
    const float s1 = sw * sx;
    float fmax_ = -3.4e38f, famax_ = 0.0f;
#pragma unroll
    for (int fc = 0; fc < 4; ++fc) {
      const float bvs = bias[n0 + wc * 64 + fc * 16 + r15] * s1;
#pragma unroll
      for (int fr = 0; fr < 4; ++fr)
#pragma unroll
        for (int r = 0; r < 4; ++r) {
          const float f = fmaf((float)acc[fr][fc][r], s1, bvs);
          fmax_ = fmaxf(fmax_, f);
          famax_ = fmaxf(famax_, fabsf(f));
        }
    }
#pragma unroll
    for (int off = 32; off > 0; off >>= 1) {
      fmax_ = fmaxf(fmax_, __shfl_xor(fmax_, off, 64));
      famax_ = fmaxf(famax_, __shfl_xor(famax_, off, 64));
    }
    __syncthreads();             // all compute() LDS reads complete
    if (lane == 0) { red8[wave] = fmax_; red8[4 + wave] = famax_; }
    __syncthreads();
    // partial stores f-units max (reducer called with pre_scaled=1!)
    const float bfmax = fmaxf(fmaxf(red8[0], red8[1]), fmaxf(red8[2], red8[3]));
    const float F = fmaxf(fmaxf(fmaxf(red8[4], red8[5]), fmaxf(red8[6], red8[7])), 1e-20f);
    if (t == 0) { partial[tid0] = bfmax; fscale[tid0] = F; }
    const float inv = 32767.0f / F;
    short* qt16 = (short*)lds;   // 32 KiB repack tile, col ^ (q4<<4) swizzle
#pragma unroll
    for (int fc = 0; fc < 4; ++fc) {
      const int col = wc * 64 + fc * 16 + r15;
      const float bvs = bias[n0 + col] * s1;
#pragma unroll
      for (int fr = 0; fr < 4; ++fr) {
        const int rowb = wr * 64 + fr * 16 + rb;
#pragma unroll
        for (int r = 0; r < 4; ++r) {
          const float f = fmaf((float)acc[fr][fc][r], s1, bvs);  // identical recompute
          qt16[(rowb + r) * 128 + (col ^ (q4 << 4))] = (short)(int)rintf(f * inv);
        }
      }
    }
    __syncthreads();
#pragma unroll
    for (int v = 0; v < 8; ++v) {
      const int row = v * 16 + (t >> 4);
      const int col16 = (t & 15) * 8;
      const int swz = ((row >> 2) & 3) << 4;
      *(v4i*)(&out_i16[(m0 + row) * (size_t)N + n0 + col16]) =
          *(const v4i*)(&qt16[row * 128 + (col16 ^ swz)]);
    }
  }
}

__global__ __launch_bounds__(256, 4)
void gemm1_fused_kernel(const int8_t* A, const int8_t* B, const float* bias,
                        const unsigned* scal, float* partial, float* fscale,
                        short* h16, int N, int K, int GN) {
  gemm_body<3, 128>(A, B, bias, scal, partial, fscale, nullptr, h16, nullptr, N, K, GN);
}

__global__ __launch_bounds__(256, 4)
void gemm1_absmax_kernel(const int8_t* A, const int8_t* B, const float* bias,
                         const unsigned* scal, float* partial, int N, int K, int GN) {
  gemm_body<0, 128>(A, B, bias, scal, partial, nullptr, nullptr, nullptr, nullptr, N, K, GN);
}

__global__ __launch_bounds__(256, 4)
void gemm1_quant_kernel(const int8_t* A, const int8_t* B, const float* bias,
                        const unsigned* scal, int8_t* out_i8, int N, int K, int GN) {
  gemm_body<1, 128>(A, B, bias, scal, nullptr, nullptr, out_i8, nullptr, nullptr, N, K, GN);
}

__global__ __launch_bounds__(256, 5)
void gemm2_out_kernel(const int8_t* A, const int8_t* B, const float* bias,
                      const unsigned* scal, float* out_f32, int N, int K, int GN) {
  gemm_body<2, 64>(A, B, bias, scal, nullptr, nullptr, nullptr, nullptr, out_f32, N, K, GN);
}

extern "C" void kernel_launch(void* const* d_in, const int* in_sizes, int n_in,
                              void* d_out, int out_size, void* d_ws, size_t ws_size,
                              hipStream_t stream) {
  const float* x   = (const float*)d_in[0];
  const float* sxp = (const float*)d_in[1];
  const float* w1  = (const float*)d_in[2];
  const float* b1  = (const float*)d_in[3];
  const float* w2  = (const float*)d_in[4];
  const float* b2  = (const float*)d_in[5];

  const int H = in_sizes[3];      // 1536
  const int D = in_sizes[5];      // 384
  const int M = in_sizes[0] / D;  // 25216 = 197*128
  const int GM1 = M / 128;        // 197
  const int GM2 = M / 64;         // 394
  const int GN1 = H / 128;        // 12
  const int GN2 = D / 128;        // 3

  uint8_t* ws = (uint8_t*)d_ws;
  unsigned* scal = (unsigned*)ws;  // [0]=max|x2| [1]=max|w1| [2]=max|w2| [3]=max|g|
  size_t off = 256;
  float* partial = (float*)(ws + off); off += 16384;
  float* fscale  = (float*)(ws + off); off += 16384;
  int8_t* qx  = (int8_t*)(ws + off); off += (size_t)M * D;
  int8_t* qw1 = (int8_t*)(ws + off); off += (size_t)H * D;
  int8_t* qw2 = (int8_t*)(ws + off); off += (size_t)D * H;
  int8_t* qh  = (int8_t*)(ws + off); off += (size_t)M * H;
  short*  h16 = (short*)(ws + off);
  const size_t need = off + 2ull * M * H;
  const bool fused = (ws_size >= need);
  (void)n_in; (void)out_size;

  hipMemsetAsync(scal, 0, 16, stream);

  absmax3_kernel<<<dim3(768), dim3(256), 0, stream>>>(
      x, M * D / 4, sxp, w1, H * D / 4, w2, D * H / 4, scal);

  quantize3_kernel<<<dim3(2304), dim3(256), 0, stream>>>(
      x, M * D / 4, sxp, w1, H * D / 4, w2, D * H / 4, scal, qx, qw1, qw2);

  dim3 blk(256);
  dim3 g1(GN1 * GM1);  // 2364, 1D grid, swizzled in-kernel
  if (fused) {
    gemm1_fused_kernel<<<g1, blk, 0, stream>>>(qx, qw1, b1, scal, partial, fscale, h16, H, D, GN1);
    reduce_scale_kernel<<<1, 256, 0, stream>>>(partial, GM1 * GN1, scal, 1);
    quanth_kernel<<<g1, blk, 0, stream>>>(h16, fscale, scal, qh, H, GN1);
  } else {
    gemm1_absmax_kernel<<<g1, blk, 0, stream>>>(qx, qw1, b1, scal, partial, H, D, GN1);
    reduce_scale_kernel<<<1, 256, 0, stream>>>(partial, GM1 * GN1, scal, 0);
    gemm1_quant_kernel<<<g1, blk, 0, stream>>>(qx, qw1, b1, scal, qh, H, D, GN1);
  }

  dim3 g2(GN2 * GM2);  // 1182
  gemm2_out_kernel<<<g2, blk, 0, stream>>>(qh, qw2, b2, scal, (float*)d_out, D, H, GN2);
}